// Round 8
// baseline (398.705 us; speedup 1.0000x reference)
//
#include <hip/hip_runtime.h>

typedef _Float16 f16x8 __attribute__((ext_vector_type(8)));
typedef _Float16 f16x4 __attribute__((ext_vector_type(4)));
typedef float f32x4 __attribute__((ext_vector_type(4)));

#define HH 2000
#define WW 1000
#define HWSZ (HH * WW)
#define NEG_INF (-3.0e38f)

// ---- monotone float<->uint encoding for atomicMax on floats ----
__device__ __forceinline__ unsigned fenc(float f) {
    unsigned u = __float_as_uint(f);
    return (u & 0x80000000u) ? ~u : (u | 0x80000000u);
}
__device__ __forceinline__ float fdec(unsigned k) {
    unsigned u = (k & 0x80000000u) ? (k & 0x7fffffffu) : ~k;
    return __uint_as_float(u);
}

__global__ void init_buckets(unsigned* __restrict__ buck, int n) {
    int i = blockIdx.x * blockDim.x + threadIdx.x;
    if (i < n) buck[i] = 0u;
}

__global__ void decode_buckets(unsigned* __restrict__ buck, int n) {
    int i = blockIdx.x * blockDim.x + threadIdx.x;
    if (i < n) {
        unsigned k = buck[i];
        ((float*)buck)[i] = fdec(k);
    }
}

// MFMA 16x16x32 f16 layouts (gfx950, verified R6/R7 absmax=2e-3):
//   A: lane holds A[m=lane&15][k=(lane>>4)*8+j]
//   B: lane holds B[k=(lane>>4)*8+j][n=lane&15]
//   D: lane holds D[row=(lane>>4)*4+reg][col=lane&15]
// A = weights (m = out-ch), B = activations (n = pixel).
// Biases folded in via constant-1 channel (K 9->10, 18->19, 36->37).
// R8: 4 independent row-chains per iteration + input prefetch + short epilogue.

__global__ __launch_bounds__(256) void mlp_max_mfma(
    const float* __restrict__ in,
    const float* __restrict__ w1, const float* __restrict__ b1,
    const float* __restrict__ w2, const float* __restrict__ b2,
    const float* __restrict__ w3, const float* __restrict__ b3,
    const float* __restrict__ w4, const float* __restrict__ b4,
    unsigned* __restrict__ rowbuck, unsigned* __restrict__ colbuck) {
    // per wave: 4 row-slots x (buf1[16][40] + buf2[16][40]) halves = 10 KB.
    // stride 40 halves = 80B keeps every b128 16B-aligned. Every byte read
    // is written earlier in the same iteration -> no zero-init needed.
    __shared__ _Float16 lds[4][4 * 1280];

    const int tx = threadIdx.x;   // 0..63
    const int wv = threadIdx.y;   // 0..3
    const int px = tx & 15;
    const int q = tx >> 4;

    // ---- weight A-fragments (persistent, reused every iteration) ----
    f16x8 A1[2], A2[3], A3s0[3], A3s1[3];
#pragma unroll
    for (int t = 0; t < 2; ++t) {
        const int m = t * 16 + px;
#pragma unroll
        for (int j = 0; j < 8; ++j) {
            const int k = q * 8 + j;
            float v = 0.f;
            if (m < 18) {
                if (k < 9) v = w1[m * 9 + k];
                else if (k == 9) v = b1[m];
            }
            A1[t][j] = (_Float16)v;
        }
    }
#pragma unroll
    for (int t = 0; t < 3; ++t) {
        const int m = t * 16 + px;
#pragma unroll
        for (int j = 0; j < 8; ++j) {
            const int k = q * 8 + j;
            float v = 0.f;
            if (m < 36) {
                if (k < 18) v = w2[m * 18 + k];
                else if (k == 18) v = b2[m];
            }
            A2[t][j] = (_Float16)v;
        }
    }
#pragma unroll
    for (int t = 0; t < 3; ++t) {
        const int m = t * 16 + px;
#pragma unroll
        for (int j = 0; j < 8; ++j) {
            const int k = q * 8 + j;
            float v = 0.f;
            if (m < 36 && k < 32) v = w3[m * 36 + k];
            A3s0[t][j] = (_Float16)v;
            float v2 = 0.f;
            const int k2 = 32 + k;  // slice 2: ch 32..35 real, 36 = bias
            if (m < 36) {
                if (k2 < 36) v2 = w3[m * 36 + k2];
                else if (k2 == 36) v2 = b3[m];
            }
            A3s1[t][j] = (_Float16)v2;
        }
    }

    float w4r[3][4];
#pragma unroll
    for (int t = 0; t < 3; ++t)
#pragma unroll
        for (int rg = 0; rg < 4; ++rg) {
            const int ch = t * 16 + q * 4 + rg;
            w4r[t][rg] = (ch < 36) ? w4[ch] : 0.f;
        }
    const float b4s = b4[0];

    const int col = blockIdx.x * 64 + wv * 16 + px;
    const int colc = (col < WW) ? col : (WW - 1);
    const bool colok = (col < WW);
    const int rb = blockIdx.y * 16;

    float colmax = NEG_INF;
    const f32x4 zf4 = {0.f, 0.f, 0.f, 0.f};

    auto load_bins = [&](f16x8* dst, int row0) {
#pragma unroll
        for (int rr = 0; rr < 4; ++rr) {
#pragma unroll
            for (int j = 0; j < 8; ++j) {
                const int c = q * 8 + j;
                float v = 0.f;
                if (c < 9) v = in[c * HWSZ + (row0 + rr) * WW + colc];
                else if (c == 9) v = 1.f;
                dst[rr][j] = (_Float16)v;
            }
        }
    };

    f16x8 binn[4];
    load_bins(binn, rb);  // prefetch rows rb..rb+3

#pragma unroll 1
    for (int it = 0; it < 4; ++it) {
        f16x8 binc[4];
#pragma unroll
        for (int rr = 0; rr < 4; ++rr) binc[rr] = binn[rr];
        if (it < 3) load_bins(binn, rb + (it + 1) * 4);  // hide global latency

        const int r0 = rb + it * 4;

        // ---- layer 1 (bias via k=9) ----
        f32x4 D1[4][2];
#pragma unroll
        for (int rr = 0; rr < 4; ++rr)
#pragma unroll
            for (int t = 0; t < 2; ++t)
                D1[rr][t] = __builtin_amdgcn_mfma_f32_16x16x32_f16(A1[t], binc[rr], zf4, 0, 0, 0);

#pragma unroll
        for (int rr = 0; rr < 4; ++rr)
#pragma unroll
            for (int t = 0; t < 2; ++t) {
                f16x4 h;
#pragma unroll
                for (int rg = 0; rg < 4; ++rg) h[rg] = (_Float16)fmaxf(D1[rr][t][rg], 0.f);
                if (t == 1 && q == 0) h[2] = (_Float16)1.f;  // ch18 = bias channel
                *(f16x4*)&lds[wv][rr * 1280 + px * 40 + t * 16 + q * 4] = h;
            }
        f16x8 B2[4];
#pragma unroll
        for (int rr = 0; rr < 4; ++rr)
            B2[rr] = *(const f16x8*)&lds[wv][rr * 1280 + px * 40 + q * 8];

        // ---- layer 2 (bias via k=18) ----
        f32x4 D2[4][3];
#pragma unroll
        for (int rr = 0; rr < 4; ++rr)
#pragma unroll
            for (int t = 0; t < 3; ++t)
                D2[rr][t] = __builtin_amdgcn_mfma_f32_16x16x32_f16(A2[t], B2[rr], zf4, 0, 0, 0);

#pragma unroll
        for (int rr = 0; rr < 4; ++rr)
#pragma unroll
            for (int t = 0; t < 3; ++t) {
                f16x4 h;
#pragma unroll
                for (int rg = 0; rg < 4; ++rg) h[rg] = (_Float16)fmaxf(D2[rr][t][rg], 0.f);
                if (t < 2) {
                    *(f16x4*)&lds[wv][rr * 1280 + 640 + px * 40 + t * 16 + q * 4] = h;
                } else if (q == 0) {  // ch 32..35
                    *(f16x4*)&lds[wv][rr * 1280 + 640 + px * 40 + 32] = h;
                }
            }
        f16x8 B30[4], B31[4];
#pragma unroll
        for (int rr = 0; rr < 4; ++rr) {
            B30[rr] = *(const f16x8*)&lds[wv][rr * 1280 + 640 + px * 40 + q * 8];
            f16x8 z = {0, 0, 0, 0, 0, 0, 0, 0};
            if (q == 0) {  // slice2: j0..3 = ch32..35, j4 = bias (=1)
                const f16x4 t0 = *(const f16x4*)&lds[wv][rr * 1280 + 640 + px * 40 + 32];
#pragma unroll
                for (int j = 0; j < 4; ++j) z[j] = t0[j];
                z[4] = (_Float16)1.f;
            }
            B31[rr] = z;
        }

        // ---- layer 3 (two K-slices, bias via k=36) ----
        f32x4 D3[4][3];
#pragma unroll
        for (int rr = 0; rr < 4; ++rr)
#pragma unroll
            for (int t = 0; t < 3; ++t) {
                D3[rr][t] = __builtin_amdgcn_mfma_f32_16x16x32_f16(A3s0[t], B30[rr], zf4, 0, 0, 0);
                D3[rr][t] = __builtin_amdgcn_mfma_f32_16x16x32_f16(A3s1[t], B31[rr], D3[rr][t], 0, 0, 0);
            }

        // ---- layer 4 epilogue: tree-summed dot, 2 shuffles, direct atomics ----
#pragma unroll
        for (int rr = 0; rr < 4; ++rr) {
            float p0 = 0.f, p1 = 0.f, p2 = 0.f;
#pragma unroll
            for (int rg = 0; rg < 4; ++rg) {
                p0 = fmaf(w4r[0][rg], fmaxf(D3[rr][0][rg], 0.f), p0);
                p1 = fmaf(w4r[1][rg], fmaxf(D3[rr][1][rg], 0.f), p1);
                p2 = fmaf(w4r[2][rg], fmaxf(D3[rr][2][rg], 0.f), p2);
            }
            float s = (p0 + p1) + p2;
            s += __shfl_xor(s, 16, 64);
            s += __shfl_xor(s, 32, 64);   // now every lane holds s(px) for this row
            s += b4s;
            s = colok ? s : NEG_INF;
            colmax = fmaxf(colmax, s);
            if (q == 0) atomicMax(&rowbuck[r0 + rr], fenc(s));  // 16 lanes, fire-and-forget
        }
    }

    if (q == 0 && colok) atomicMax(&colbuck[col], fenc(colmax));
}

extern "C" void kernel_launch(void* const* d_in, const int* in_sizes, int n_in,
                              void* d_out, int out_size, void* d_ws, size_t ws_size,
                              hipStream_t stream) {
    const float* in = (const float*)d_in[0];
    // d_in[1] = T_out (unused), d_in[2] = T_indices (identity, unused)
    const float* w1 = (const float*)d_in[3];
    const float* b1 = (const float*)d_in[4];
    const float* w2 = (const float*)d_in[5];
    const float* b2 = (const float*)d_in[6];
    const float* w3 = (const float*)d_in[7];
    const float* b3 = (const float*)d_in[8];
    const float* w4 = (const float*)d_in[9];
    const float* b4 = (const float*)d_in[10];

    unsigned* buck = (unsigned*)d_out;  // [0,2000) row maxes, [2000,3000) col maxes

    init_buckets<<<(3000 + 255) / 256, 256, 0, stream>>>(buck, 3000);

    dim3 block(64, 4);
    dim3 grid(16, 125);  // 64 cols x 16 rows per block
    mlp_max_mfma<<<grid, block, 0, stream>>>(in, w1, b1, w2, b2, w3, b3, w4, b4,
                                             buck, buck + 2000);

    decode_buckets<<<(3000 + 255) / 256, 256, 0, stream>>>(buck, 3000);
}

// Round 9
// 375.672 us; speedup vs baseline: 1.0613x; 1.0613x over previous
//
#include <hip/hip_runtime.h>

typedef _Float16 f16x8 __attribute__((ext_vector_type(8)));
typedef _Float16 f16x4 __attribute__((ext_vector_type(4)));
typedef float f32x4 __attribute__((ext_vector_type(4)));

#define HH 2000
#define WW 1000
#define HWSZ (HH * WW)
#define NEG_INF (-3.0e38f)

// ---- monotone float<->uint encoding for atomicMax on floats ----
__device__ __forceinline__ unsigned fenc(float f) {
    unsigned u = __float_as_uint(f);
    return (u & 0x80000000u) ? ~u : (u | 0x80000000u);
}
__device__ __forceinline__ float fdec(unsigned k) {
    unsigned u = (k & 0x80000000u) ? (k & 0x7fffffffu) : ~k;
    return __uint_as_float(u);
}

__global__ void init_buckets(unsigned* __restrict__ buck, int n) {
    int i = blockIdx.x * blockDim.x + threadIdx.x;
    if (i < n) buck[i] = 0u;
}

__global__ void decode_buckets(unsigned* __restrict__ buck, int n) {
    int i = blockIdx.x * blockDim.x + threadIdx.x;
    if (i < n) {
        unsigned k = buck[i];
        ((float*)buck)[i] = fdec(k);
    }
}

// MFMA 16x16x32 f16 layouts (gfx950, verified R6-R8 absmax=2e-3):
//   A: lane holds A[m=lane&15][k=(lane>>4)*8+j]
//   B: lane holds B[k=(lane>>4)*8+j][n=lane&15]
//   D: lane holds D[row=(lane>>4)*4+reg][col=lane&15]
// A = weights (m = out-ch), B = activations (n = pixel).
// Biases folded in via constant-1 channel (K 9->10, 18->19, 36->37).
// R9 = R7 equilibrium (2-row ILP, 20KB LDS) + input prefetch + short epilogue
//      + 8 rows/wave (grid 16x250). R8 taught: >2 chains or >20KB LDS collapses.

__global__ __launch_bounds__(256) void mlp_max_mfma(
    const float* __restrict__ in,
    const float* __restrict__ w1, const float* __restrict__ b1,
    const float* __restrict__ w2, const float* __restrict__ b2,
    const float* __restrict__ w3, const float* __restrict__ b3,
    const float* __restrict__ w4, const float* __restrict__ b4,
    unsigned* __restrict__ rowbuck, unsigned* __restrict__ colbuck) {
    // per wave: 2 row-slots x (buf1[16][40] + buf2[16][40]) halves = 5 KB.
    // stride 40 halves = 80B keeps every b128 16B-aligned. Every byte read
    // is written earlier in the same iteration -> no zero-init needed.
    __shared__ _Float16 lds[4][2 * 1280];

    const int tx = threadIdx.x;   // 0..63
    const int wv = threadIdx.y;   // 0..3
    const int px = tx & 15;
    const int q = tx >> 4;

    _Float16* s0buf1 = &lds[wv][0];
    _Float16* s0buf2 = &lds[wv][640];
    _Float16* s1buf1 = &lds[wv][1280];
    _Float16* s1buf2 = &lds[wv][1920];

    // ---- weight A-fragments (persistent, reused every iteration) ----
    f16x8 A1[2], A2[3], A3s0[3], A3s1[3];
#pragma unroll
    for (int t = 0; t < 2; ++t) {
        const int m = t * 16 + px;
#pragma unroll
        for (int j = 0; j < 8; ++j) {
            const int k = q * 8 + j;
            float v = 0.f;
            if (m < 18) {
                if (k < 9) v = w1[m * 9 + k];
                else if (k == 9) v = b1[m];
            }
            A1[t][j] = (_Float16)v;
        }
    }
#pragma unroll
    for (int t = 0; t < 3; ++t) {
        const int m = t * 16 + px;
#pragma unroll
        for (int j = 0; j < 8; ++j) {
            const int k = q * 8 + j;
            float v = 0.f;
            if (m < 36) {
                if (k < 18) v = w2[m * 18 + k];
                else if (k == 18) v = b2[m];
            }
            A2[t][j] = (_Float16)v;
        }
    }
#pragma unroll
    for (int t = 0; t < 3; ++t) {
        const int m = t * 16 + px;
#pragma unroll
        for (int j = 0; j < 8; ++j) {
            const int k = q * 8 + j;
            float v = 0.f;
            if (m < 36 && k < 32) v = w3[m * 36 + k];
            A3s0[t][j] = (_Float16)v;
            float v2 = 0.f;
            const int k2 = 32 + k;  // slice 2: ch 32..35 real, 36 = bias
            if (m < 36) {
                if (k2 < 36) v2 = w3[m * 36 + k2];
                else if (k2 == 36) v2 = b3[m];
            }
            A3s1[t][j] = (_Float16)v2;
        }
    }

    float w4r[3][4];
#pragma unroll
    for (int t = 0; t < 3; ++t)
#pragma unroll
        for (int rg = 0; rg < 4; ++rg) {
            const int ch = t * 16 + q * 4 + rg;
            w4r[t][rg] = (ch < 36) ? w4[ch] : 0.f;
        }
    const float b4s = b4[0];

    const int col = blockIdx.x * 64 + wv * 16 + px;
    const int colc = (col < WW) ? col : (WW - 1);
    const bool colok = (col < WW);
    const int rb = blockIdx.y * 8;

    float colmax = NEG_INF;
    const f32x4 zf4 = {0.f, 0.f, 0.f, 0.f};

    auto load2 = [&](f16x8* dst, int row0) {
#pragma unroll
        for (int rr = 0; rr < 2; ++rr) {
#pragma unroll
            for (int j = 0; j < 8; ++j) {
                const int c = q * 8 + j;
                float v = 0.f;
                if (c < 9) v = in[c * HWSZ + (row0 + rr) * WW + colc];
                else if (c == 9) v = 1.f;
                dst[rr][j] = (_Float16)v;
            }
        }
    };

    f16x8 binn[2];
    load2(binn, rb);  // prefetch first 2 rows

#pragma unroll 1
    for (int it = 0; it < 4; ++it) {
        const f16x8 bin0 = binn[0];
        const f16x8 bin1 = binn[1];
        if (it < 3) load2(binn, rb + (it + 1) * 2);  // hide global latency

        const int r0 = rb + it * 2;
        const int r1 = r0 + 1;

        // ---- layer 1 (bias via k=9) ----
        f32x4 D1a[2], D1b[2];
#pragma unroll
        for (int t = 0; t < 2; ++t) {
            D1a[t] = __builtin_amdgcn_mfma_f32_16x16x32_f16(A1[t], bin0, zf4, 0, 0, 0);
            D1b[t] = __builtin_amdgcn_mfma_f32_16x16x32_f16(A1[t], bin1, zf4, 0, 0, 0);
        }
#pragma unroll
        for (int t = 0; t < 2; ++t) {
            f16x4 h0, h1;
#pragma unroll
            for (int rg = 0; rg < 4; ++rg) {
                h0[rg] = (_Float16)fmaxf(D1a[t][rg], 0.f);
                h1[rg] = (_Float16)fmaxf(D1b[t][rg], 0.f);
            }
            if (t == 1 && q == 0) { h0[2] = (_Float16)1.f; h1[2] = (_Float16)1.f; }  // ch18 = 1
            *(f16x4*)&s0buf1[px * 40 + t * 16 + q * 4] = h0;
            *(f16x4*)&s1buf1[px * 40 + t * 16 + q * 4] = h1;
        }
        const f16x8 B2a = *(const f16x8*)&s0buf1[px * 40 + q * 8];
        const f16x8 B2b = *(const f16x8*)&s1buf1[px * 40 + q * 8];

        // ---- layer 2 (bias via k=18) ----
        f32x4 D2a[3], D2b[3];
#pragma unroll
        for (int t = 0; t < 3; ++t) {
            D2a[t] = __builtin_amdgcn_mfma_f32_16x16x32_f16(A2[t], B2a, zf4, 0, 0, 0);
            D2b[t] = __builtin_amdgcn_mfma_f32_16x16x32_f16(A2[t], B2b, zf4, 0, 0, 0);
        }
#pragma unroll
        for (int t = 0; t < 3; ++t) {
            f16x4 h0, h1;
#pragma unroll
            for (int rg = 0; rg < 4; ++rg) {
                h0[rg] = (_Float16)fmaxf(D2a[t][rg], 0.f);
                h1[rg] = (_Float16)fmaxf(D2b[t][rg], 0.f);
            }
            if (t < 2) {
                *(f16x4*)&s0buf2[px * 40 + t * 16 + q * 4] = h0;
                *(f16x4*)&s1buf2[px * 40 + t * 16 + q * 4] = h1;
            } else if (q == 0) {  // ch 32..35 only
                *(f16x4*)&s0buf2[px * 40 + 32] = h0;
                *(f16x4*)&s1buf2[px * 40 + 32] = h1;
            }
        }
        const f16x8 B3a0 = *(const f16x8*)&s0buf2[px * 40 + q * 8];
        const f16x8 B3b0 = *(const f16x8*)&s1buf2[px * 40 + q * 8];
        f16x8 B3a1 = {0, 0, 0, 0, 0, 0, 0, 0};
        f16x8 B3b1 = {0, 0, 0, 0, 0, 0, 0, 0};
        if (q == 0) {  // slice2: j0..3 = ch32..35, j4 = bias (=1)
            const f16x4 t0 = *(const f16x4*)&s0buf2[px * 40 + 32];
            const f16x4 t1 = *(const f16x4*)&s1buf2[px * 40 + 32];
#pragma unroll
            for (int j = 0; j < 4; ++j) { B3a1[j] = t0[j]; B3b1[j] = t1[j]; }
            B3a1[4] = (_Float16)1.f;
            B3b1[4] = (_Float16)1.f;
        }

        // ---- layer 3 (two K-slices, bias via k=36) ----
        f32x4 D3a[3], D3b[3];
#pragma unroll
        for (int t = 0; t < 3; ++t) {
            D3a[t] = __builtin_amdgcn_mfma_f32_16x16x32_f16(A3s0[t], B3a0, zf4, 0, 0, 0);
            D3a[t] = __builtin_amdgcn_mfma_f32_16x16x32_f16(A3s1[t], B3a1, D3a[t], 0, 0, 0);
            D3b[t] = __builtin_amdgcn_mfma_f32_16x16x32_f16(A3s0[t], B3b0, zf4, 0, 0, 0);
            D3b[t] = __builtin_amdgcn_mfma_f32_16x16x32_f16(A3s1[t], B3b1, D3b[t], 0, 0, 0);
        }

        // ---- layer 4 epilogue: tree-sum, 2 shuffles, 16-lane direct atomics ----
        {
            float p0a = 0.f, p1a = 0.f, p2a = 0.f;
            float p0b = 0.f, p1b = 0.f, p2b = 0.f;
#pragma unroll
            for (int rg = 0; rg < 4; ++rg) {
                p0a = fmaf(w4r[0][rg], fmaxf(D3a[0][rg], 0.f), p0a);
                p1a = fmaf(w4r[1][rg], fmaxf(D3a[1][rg], 0.f), p1a);
                p2a = fmaf(w4r[2][rg], fmaxf(D3a[2][rg], 0.f), p2a);
                p0b = fmaf(w4r[0][rg], fmaxf(D3b[0][rg], 0.f), p0b);
                p1b = fmaf(w4r[1][rg], fmaxf(D3b[1][rg], 0.f), p1b);
                p2b = fmaf(w4r[2][rg], fmaxf(D3b[2][rg], 0.f), p2b);
            }
            float sa = (p0a + p1a) + p2a;
            float sb = (p0b + p1b) + p2b;
            sa += __shfl_xor(sa, 16, 64); sb += __shfl_xor(sb, 16, 64);
            sa += __shfl_xor(sa, 32, 64); sb += __shfl_xor(sb, 32, 64);
            sa += b4s; sb += b4s;
            sa = colok ? sa : NEG_INF;
            sb = colok ? sb : NEG_INF;
            colmax = fmaxf(colmax, fmaxf(sa, sb));
            if (q == 0) {  // 16 px-lanes each own one atomic, fire-and-forget
                atomicMax(&rowbuck[r0], fenc(sa));
                atomicMax(&rowbuck[r1], fenc(sb));
            }
        }
    }

    if (q == 0 && colok) atomicMax(&colbuck[col], fenc(colmax));
}

extern "C" void kernel_launch(void* const* d_in, const int* in_sizes, int n_in,
                              void* d_out, int out_size, void* d_ws, size_t ws_size,
                              hipStream_t stream) {
    const float* in = (const float*)d_in[0];
    // d_in[1] = T_out (unused), d_in[2] = T_indices (identity, unused)
    const float* w1 = (const float*)d_in[3];
    const float* b1 = (const float*)d_in[4];
    const float* w2 = (const float*)d_in[5];
    const float* b2 = (const float*)d_in[6];
    const float* w3 = (const float*)d_in[7];
    const float* b3 = (const float*)d_in[8];
    const float* w4 = (const float*)d_in[9];
    const float* b4 = (const float*)d_in[10];

    unsigned* buck = (unsigned*)d_out;  // [0,2000) row maxes, [2000,3000) col maxes

    init_buckets<<<(3000 + 255) / 256, 256, 0, stream>>>(buck, 3000);

    dim3 block(64, 4);
    dim3 grid(16, 250);  // 64 cols x 8 rows per block
    mlp_max_mfma<<<grid, block, 0, stream>>>(in, w1, b1, w2, b2, w3, b3, w4, b4,
                                             buck, buck + 2000);

    decode_buckets<<<(3000 + 255) / 256, 256, 0, stream>>>(buck, 3000);
}

// Round 10
// 315.276 us; speedup vs baseline: 1.2646x; 1.1916x over previous
//
#include <hip/hip_runtime.h>

typedef _Float16 f16x8 __attribute__((ext_vector_type(8)));
typedef _Float16 f16x4 __attribute__((ext_vector_type(4)));
typedef float f32x4 __attribute__((ext_vector_type(4)));

#define HH 2000
#define WW 1000
#define HWSZ (HH * WW)
#define NEG_INF (-3.0e38f)

// ---- monotone float<->uint encoding for atomicMax on floats ----
__device__ __forceinline__ unsigned fenc(float f) {
    unsigned u = __float_as_uint(f);
    return (u & 0x80000000u) ? ~u : (u | 0x80000000u);
}
__device__ __forceinline__ float fdec(unsigned k) {
    unsigned u = (k & 0x80000000u) ? (k & 0x7fffffffu) : ~k;
    return __uint_as_float(u);
}

__global__ void init_buckets(unsigned* __restrict__ buck, int n) {
    int i = blockIdx.x * blockDim.x + threadIdx.x;
    if (i < n) buck[i] = 0u;
}

__global__ void decode_buckets(unsigned* __restrict__ buck, int n) {
    int i = blockIdx.x * blockDim.x + threadIdx.x;
    if (i < n) {
        unsigned k = buck[i];
        ((float*)buck)[i] = fdec(k);
    }
}

// MFMA 16x16x32 f16 layouts (gfx950, verified R6-R9 absmax=2e-3):
//   A: lane holds A[m=lane&15][k=(lane>>4)*8+j]
//   B: lane holds B[k=(lane>>4)*8+j][n=lane&15]
//   D: lane holds D[row=(lane>>4)*4+reg][col=lane&15]
// A = weights (m = out-ch), B = activations (n = pixel).
// Biases folded in via constant-1 channel (K 9->10, 18->19, 36->37).
// R10 = R7 EXACT (best measured: 160us; 2-row ILP, 20KB LDS, grid 16x125,
//       tx==0 epilogue atomics) + register prefetch of next 2 input rows.
//       R9 taught: 16-lane contended atomics poison the vmcnt queue; 2x grid
//       doubles prologue cost. Both reverted.

__global__ __launch_bounds__(256) void mlp_max_mfma(
    const float* __restrict__ in,
    const float* __restrict__ w1, const float* __restrict__ b1,
    const float* __restrict__ w2, const float* __restrict__ b2,
    const float* __restrict__ w3, const float* __restrict__ b3,
    const float* __restrict__ w4, const float* __restrict__ b4,
    unsigned* __restrict__ rowbuck, unsigned* __restrict__ colbuck) {
    // per wave: 2 row-slots x (buf1[16][40] + buf2[16][40]) halves = 5 KB.
    // stride 40 halves = 80B keeps every b128 16B-aligned. Every byte read
    // is written earlier in the same iteration -> no zero-init needed.
    __shared__ _Float16 lds[4][2 * 1280];

    const int tx = threadIdx.x;   // 0..63
    const int wv = threadIdx.y;   // 0..3
    const int px = tx & 15;
    const int q = tx >> 4;

    _Float16* s0buf1 = &lds[wv][0];
    _Float16* s0buf2 = &lds[wv][640];
    _Float16* s1buf1 = &lds[wv][1280];
    _Float16* s1buf2 = &lds[wv][1920];

    // ---- weight A-fragments (persistent, reused every iteration) ----
    f16x8 A1[2], A2[3], A3s0[3], A3s1[3];
#pragma unroll
    for (int t = 0; t < 2; ++t) {
        const int m = t * 16 + px;
#pragma unroll
        for (int j = 0; j < 8; ++j) {
            const int k = q * 8 + j;
            float v = 0.f;
            if (m < 18) {
                if (k < 9) v = w1[m * 9 + k];
                else if (k == 9) v = b1[m];
            }
            A1[t][j] = (_Float16)v;
        }
    }
#pragma unroll
    for (int t = 0; t < 3; ++t) {
        const int m = t * 16 + px;
#pragma unroll
        for (int j = 0; j < 8; ++j) {
            const int k = q * 8 + j;
            float v = 0.f;
            if (m < 36) {
                if (k < 18) v = w2[m * 18 + k];
                else if (k == 18) v = b2[m];
            }
            A2[t][j] = (_Float16)v;
        }
    }
#pragma unroll
    for (int t = 0; t < 3; ++t) {
        const int m = t * 16 + px;
#pragma unroll
        for (int j = 0; j < 8; ++j) {
            const int k = q * 8 + j;
            float v = 0.f;
            if (m < 36 && k < 32) v = w3[m * 36 + k];
            A3s0[t][j] = (_Float16)v;
            float v2 = 0.f;
            const int k2 = 32 + k;  // slice 2: ch 32..35 real, 36 = bias
            if (m < 36) {
                if (k2 < 36) v2 = w3[m * 36 + k2];
                else if (k2 == 36) v2 = b3[m];
            }
            A3s1[t][j] = (_Float16)v2;
        }
    }

    float w4r[3][4];
#pragma unroll
    for (int t = 0; t < 3; ++t)
#pragma unroll
        for (int rg = 0; rg < 4; ++rg) {
            const int ch = t * 16 + q * 4 + rg;
            w4r[t][rg] = (ch < 36) ? w4[ch] : 0.f;
        }
    const float b4s = b4[0];

    const int col = blockIdx.x * 64 + wv * 16 + px;
    const int colc = (col < WW) ? col : (WW - 1);
    const bool colok = (col < WW);
    const int rb = blockIdx.y * 16;

    float colmax = NEG_INF;
    const f32x4 zf4 = {0.f, 0.f, 0.f, 0.f};

    auto load2 = [&](f16x8* dst, int row0) {
#pragma unroll
        for (int rr = 0; rr < 2; ++rr) {
#pragma unroll
            for (int j = 0; j < 8; ++j) {
                const int c = q * 8 + j;
                float v = 0.f;
                if (c < 9) v = in[c * HWSZ + (row0 + rr) * WW + colc];
                else if (c == 9) v = 1.f;
                dst[rr][j] = (_Float16)v;
            }
        }
    };

    f16x8 binn[2];
    load2(binn, rb);  // prefetch rows rb, rb+1

#pragma unroll 1
    for (int it = 0; it < 8; ++it) {
        const f16x8 bin0 = binn[0];
        const f16x8 bin1 = binn[1];
        if (it < 7) load2(binn, rb + (it + 1) * 2);  // hide global latency

        const int r0 = rb + it * 2;
        const int r1 = r0 + 1;

        // ---- layer 1 (bias via k=9) ----
        f32x4 D1a[2], D1b[2];
#pragma unroll
        for (int t = 0; t < 2; ++t) {
            D1a[t] = __builtin_amdgcn_mfma_f32_16x16x32_f16(A1[t], bin0, zf4, 0, 0, 0);
            D1b[t] = __builtin_amdgcn_mfma_f32_16x16x32_f16(A1[t], bin1, zf4, 0, 0, 0);
        }
#pragma unroll
        for (int t = 0; t < 2; ++t) {
            f16x4 h0, h1;
#pragma unroll
            for (int rg = 0; rg < 4; ++rg) {
                h0[rg] = (_Float16)fmaxf(D1a[t][rg], 0.f);
                h1[rg] = (_Float16)fmaxf(D1b[t][rg], 0.f);
            }
            if (t == 1 && q == 0) { h0[2] = (_Float16)1.f; h1[2] = (_Float16)1.f; }  // ch18 = 1
            *(f16x4*)&s0buf1[px * 40 + t * 16 + q * 4] = h0;
            *(f16x4*)&s1buf1[px * 40 + t * 16 + q * 4] = h1;
        }
        const f16x8 B2a = *(const f16x8*)&s0buf1[px * 40 + q * 8];
        const f16x8 B2b = *(const f16x8*)&s1buf1[px * 40 + q * 8];

        // ---- layer 2 (bias via k=18) ----
        f32x4 D2a[3], D2b[3];
#pragma unroll
        for (int t = 0; t < 3; ++t) {
            D2a[t] = __builtin_amdgcn_mfma_f32_16x16x32_f16(A2[t], B2a, zf4, 0, 0, 0);
            D2b[t] = __builtin_amdgcn_mfma_f32_16x16x32_f16(A2[t], B2b, zf4, 0, 0, 0);
        }
#pragma unroll
        for (int t = 0; t < 3; ++t) {
            f16x4 h0, h1;
#pragma unroll
            for (int rg = 0; rg < 4; ++rg) {
                h0[rg] = (_Float16)fmaxf(D2a[t][rg], 0.f);
                h1[rg] = (_Float16)fmaxf(D2b[t][rg], 0.f);
            }
            if (t < 2) {
                *(f16x4*)&s0buf2[px * 40 + t * 16 + q * 4] = h0;
                *(f16x4*)&s1buf2[px * 40 + t * 16 + q * 4] = h1;
            } else if (q == 0) {  // ch 32..35 only
                *(f16x4*)&s0buf2[px * 40 + 32] = h0;
                *(f16x4*)&s1buf2[px * 40 + 32] = h1;
            }
        }
        const f16x8 B3a0 = *(const f16x8*)&s0buf2[px * 40 + q * 8];
        const f16x8 B3b0 = *(const f16x8*)&s1buf2[px * 40 + q * 8];
        f16x8 B3a1 = {0, 0, 0, 0, 0, 0, 0, 0};
        f16x8 B3b1 = {0, 0, 0, 0, 0, 0, 0, 0};
        if (q == 0) {  // slice2: j0..3 = ch32..35, j4 = bias (=1)
            const f16x4 t0 = *(const f16x4*)&s0buf2[px * 40 + 32];
            const f16x4 t1 = *(const f16x4*)&s1buf2[px * 40 + 32];
#pragma unroll
            for (int j = 0; j < 4; ++j) { B3a1[j] = t0[j]; B3b1[j] = t1[j]; }
            B3a1[4] = (_Float16)1.f;
            B3b1[4] = (_Float16)1.f;
        }

        // ---- layer 3 (two K-slices, bias via k=36) ----
        f32x4 D3a[3], D3b[3];
#pragma unroll
        for (int t = 0; t < 3; ++t) {
            D3a[t] = __builtin_amdgcn_mfma_f32_16x16x32_f16(A3s0[t], B3a0, zf4, 0, 0, 0);
            D3a[t] = __builtin_amdgcn_mfma_f32_16x16x32_f16(A3s1[t], B3a1, D3a[t], 0, 0, 0);
            D3b[t] = __builtin_amdgcn_mfma_f32_16x16x32_f16(A3s0[t], B3b0, zf4, 0, 0, 0);
            D3b[t] = __builtin_amdgcn_mfma_f32_16x16x32_f16(A3s1[t], B3b1, D3b[t], 0, 0, 0);
        }

        // ---- layer 4 epilogue (R7-proven: 2 sum-shuffles + 4 max-shuffles,
        //      single tx==0 atomic per row -> vmcnt queue stays clean) ----
        float sa = 0.f, sb = 0.f;
#pragma unroll
        for (int t = 0; t < 3; ++t)
#pragma unroll
            for (int rg = 0; rg < 4; ++rg) {
                sa = fmaf(w4r[t][rg], fmaxf(D3a[t][rg], 0.f), sa);
                sb = fmaf(w4r[t][rg], fmaxf(D3b[t][rg], 0.f), sb);
            }
        sa += __shfl_xor(sa, 16, 64); sb += __shfl_xor(sb, 16, 64);
        sa += __shfl_xor(sa, 32, 64); sb += __shfl_xor(sb, 32, 64);
        sa += b4s; sb += b4s;

        sa = colok ? sa : NEG_INF;
        sb = colok ? sb : NEG_INF;
        colmax = fmaxf(colmax, fmaxf(sa, sb));

        float m0 = sa, m1 = sb;
        m0 = fmaxf(m0, __shfl_xor(m0, 1, 64)); m1 = fmaxf(m1, __shfl_xor(m1, 1, 64));
        m0 = fmaxf(m0, __shfl_xor(m0, 2, 64)); m1 = fmaxf(m1, __shfl_xor(m1, 2, 64));
        m0 = fmaxf(m0, __shfl_xor(m0, 4, 64)); m1 = fmaxf(m1, __shfl_xor(m1, 4, 64));
        m0 = fmaxf(m0, __shfl_xor(m0, 8, 64)); m1 = fmaxf(m1, __shfl_xor(m1, 8, 64));
        if (tx == 0) {
            atomicMax(&rowbuck[r0], fenc(m0));
            atomicMax(&rowbuck[r1], fenc(m1));
        }
    }

    if (q == 0 && colok) atomicMax(&colbuck[col], fenc(colmax));
}

extern "C" void kernel_launch(void* const* d_in, const int* in_sizes, int n_in,
                              void* d_out, int out_size, void* d_ws, size_t ws_size,
                              hipStream_t stream) {
    const float* in = (const float*)d_in[0];
    // d_in[1] = T_out (unused), d_in[2] = T_indices (identity, unused)
    const float* w1 = (const float*)d_in[3];
    const float* b1 = (const float*)d_in[4];
    const float* w2 = (const float*)d_in[5];
    const float* b2 = (const float*)d_in[6];
    const float* w3 = (const float*)d_in[7];
    const float* b3 = (const float*)d_in[8];
    const float* w4 = (const float*)d_in[9];
    const float* b4 = (const float*)d_in[10];

    unsigned* buck = (unsigned*)d_out;  // [0,2000) row maxes, [2000,3000) col maxes

    init_buckets<<<(3000 + 255) / 256, 256, 0, stream>>>(buck, 3000);

    dim3 block(64, 4);
    dim3 grid(16, 125);  // 64 cols x 16 rows per block (R7 equilibrium)
    mlp_max_mfma<<<grid, block, 0, stream>>>(in, w1, b1, w2, b2, w3, b3, w4, b4,
                                             buck, buck + 2000);

    decode_buckets<<<(3000 + 255) / 256, 256, 0, stream>>>(buck, 3000);
}

// Round 11
// 252.331 us; speedup vs baseline: 1.5801x; 1.2495x over previous
//
#include <hip/hip_runtime.h>

typedef _Float16 f16x8 __attribute__((ext_vector_type(8)));
typedef _Float16 f16x4 __attribute__((ext_vector_type(4)));
typedef float f32x4 __attribute__((ext_vector_type(4)));

#define HH 2000
#define WW 1000
#define HWSZ (HH * WW)
#define NEG_INF (-3.0e38f)

// ---- monotone float<->uint encoding for atomicMax on floats ----
__device__ __forceinline__ unsigned fenc(float f) {
    unsigned u = __float_as_uint(f);
    return (u & 0x80000000u) ? ~u : (u | 0x80000000u);
}
__device__ __forceinline__ float fdec(unsigned k) {
    unsigned u = (k & 0x80000000u) ? (k & 0x7fffffffu) : ~k;
    return __uint_as_float(u);
}

__global__ void init_buckets(unsigned* __restrict__ buck, int n) {
    int i = blockIdx.x * blockDim.x + threadIdx.x;
    if (i < n) buck[i] = 0u;
}

__global__ void decode_buckets(unsigned* __restrict__ buck, int n) {
    int i = blockIdx.x * blockDim.x + threadIdx.x;
    if (i < n) {
        unsigned k = buck[i];
        ((float*)buck)[i] = fdec(k);
    }
}

// MFMA 16x16x32 f16 layouts (gfx950, verified R6-R10 absmax=2e-3):
//   A: lane holds A[m=lane&15][k=(lane>>4)*8+j]
//   B: lane holds B[k=(lane>>4)*8+j][n=lane&15]
//   D: lane holds D[row=(lane>>4)*4+reg][col=lane&15]
// A = weights (m = out-ch), B = activations (n = pixel).
// Biases folded in via constant-1 channel (K 9->10, 18->19, 36->37).
//
// R11 = R7 EXACT (best measured: 160us) with ONE change: row-max atomics
// moved OUT of the K-loop. Rationale (R9/R10 forensics): the loop-top
// s_waitcnt vmcnt(0) before the first MFMA drains the previous iteration's
// contended global atomicMax (~1000 cyc round trip) every iteration. Row
// maxes now go to LDS (lgkm pipe, never drained in-loop); one 16-atomic
// flush per block after __syncthreads. Prefetch NOT used (R10: 160->206).

__global__ __launch_bounds__(256) void mlp_max_mfma(
    const float* __restrict__ in,
    const float* __restrict__ w1, const float* __restrict__ b1,
    const float* __restrict__ w2, const float* __restrict__ b2,
    const float* __restrict__ w3, const float* __restrict__ b3,
    const float* __restrict__ w4, const float* __restrict__ b4,
    unsigned* __restrict__ rowbuck, unsigned* __restrict__ colbuck) {
    // per wave: 2 row-slots x (buf1[16][40] + buf2[16][40]) halves = 5 KB.
    // stride 40 halves = 80B keeps every b128 16B-aligned. Every byte read
    // is written earlier in the same iteration -> no zero-init needed.
    __shared__ _Float16 lds[4][2 * 1280];
    __shared__ float rowmax_s[4][16];   // [wave][row-in-block]

    const int tx = threadIdx.x;   // 0..63
    const int wv = threadIdx.y;   // 0..3
    const int px = tx & 15;
    const int q = tx >> 4;

    _Float16* s0buf1 = &lds[wv][0];
    _Float16* s0buf2 = &lds[wv][640];
    _Float16* s1buf1 = &lds[wv][1280];
    _Float16* s1buf2 = &lds[wv][1920];

    // ---- weight A-fragments (persistent, reused every iteration) ----
    f16x8 A1[2], A2[3], A3s0[3], A3s1[3];
#pragma unroll
    for (int t = 0; t < 2; ++t) {
        const int m = t * 16 + px;
#pragma unroll
        for (int j = 0; j < 8; ++j) {
            const int k = q * 8 + j;
            float v = 0.f;
            if (m < 18) {
                if (k < 9) v = w1[m * 9 + k];
                else if (k == 9) v = b1[m];
            }
            A1[t][j] = (_Float16)v;
        }
    }
#pragma unroll
    for (int t = 0; t < 3; ++t) {
        const int m = t * 16 + px;
#pragma unroll
        for (int j = 0; j < 8; ++j) {
            const int k = q * 8 + j;
            float v = 0.f;
            if (m < 36) {
                if (k < 18) v = w2[m * 18 + k];
                else if (k == 18) v = b2[m];
            }
            A2[t][j] = (_Float16)v;
        }
    }
#pragma unroll
    for (int t = 0; t < 3; ++t) {
        const int m = t * 16 + px;
#pragma unroll
        for (int j = 0; j < 8; ++j) {
            const int k = q * 8 + j;
            float v = 0.f;
            if (m < 36 && k < 32) v = w3[m * 36 + k];
            A3s0[t][j] = (_Float16)v;
            float v2 = 0.f;
            const int k2 = 32 + k;  // slice 2: ch 32..35 real, 36 = bias
            if (m < 36) {
                if (k2 < 36) v2 = w3[m * 36 + k2];
                else if (k2 == 36) v2 = b3[m];
            }
            A3s1[t][j] = (_Float16)v2;
        }
    }

    float w4r[3][4];
#pragma unroll
    for (int t = 0; t < 3; ++t)
#pragma unroll
        for (int rg = 0; rg < 4; ++rg) {
            const int ch = t * 16 + q * 4 + rg;
            w4r[t][rg] = (ch < 36) ? w4[ch] : 0.f;
        }
    const float b4s = b4[0];

    const int col = blockIdx.x * 64 + wv * 16 + px;
    const int colc = (col < WW) ? col : (WW - 1);
    const bool colok = (col < WW);
    const int rb = blockIdx.y * 16;

    float colmax = NEG_INF;
    const f32x4 zf4 = {0.f, 0.f, 0.f, 0.f};

#pragma unroll 1
    for (int it = 0; it < 8; ++it) {
        const int r0 = rb + it * 2;
        const int r1 = r0 + 1;

        // ---- inputs, both rows (K=10: ch 0..8 + constant-1 bias channel) ----
        f16x8 bin0, bin1;
#pragma unroll
        for (int j = 0; j < 8; ++j) {
            const int c = q * 8 + j;
            float v0 = 0.f, v1 = 0.f;
            if (c < 9) {
                v0 = in[c * HWSZ + r0 * WW + colc];
                v1 = in[c * HWSZ + r1 * WW + colc];
            } else if (c == 9) {
                v0 = 1.f; v1 = 1.f;
            }
            bin0[j] = (_Float16)v0;
            bin1[j] = (_Float16)v1;
        }

        // ---- layer 1 (bias via k=9) ----
        f32x4 D1a[2], D1b[2];
#pragma unroll
        for (int t = 0; t < 2; ++t) {
            D1a[t] = __builtin_amdgcn_mfma_f32_16x16x32_f16(A1[t], bin0, zf4, 0, 0, 0);
            D1b[t] = __builtin_amdgcn_mfma_f32_16x16x32_f16(A1[t], bin1, zf4, 0, 0, 0);
        }
#pragma unroll
        for (int t = 0; t < 2; ++t) {
            f16x4 h0, h1;
#pragma unroll
            for (int rg = 0; rg < 4; ++rg) {
                h0[rg] = (_Float16)fmaxf(D1a[t][rg], 0.f);
                h1[rg] = (_Float16)fmaxf(D1b[t][rg], 0.f);
            }
            if (t == 1 && q == 0) { h0[2] = (_Float16)1.f; h1[2] = (_Float16)1.f; }  // ch18 = 1
            *(f16x4*)&s0buf1[px * 40 + t * 16 + q * 4] = h0;
            *(f16x4*)&s1buf1[px * 40 + t * 16 + q * 4] = h1;
        }
        const f16x8 B2a = *(const f16x8*)&s0buf1[px * 40 + q * 8];
        const f16x8 B2b = *(const f16x8*)&s1buf1[px * 40 + q * 8];

        // ---- layer 2 (bias via k=18) ----
        f32x4 D2a[3], D2b[3];
#pragma unroll
        for (int t = 0; t < 3; ++t) {
            D2a[t] = __builtin_amdgcn_mfma_f32_16x16x32_f16(A2[t], B2a, zf4, 0, 0, 0);
            D2b[t] = __builtin_amdgcn_mfma_f32_16x16x32_f16(A2[t], B2b, zf4, 0, 0, 0);
        }
#pragma unroll
        for (int t = 0; t < 3; ++t) {
            f16x4 h0, h1;
#pragma unroll
            for (int rg = 0; rg < 4; ++rg) {
                h0[rg] = (_Float16)fmaxf(D2a[t][rg], 0.f);
                h1[rg] = (_Float16)fmaxf(D2b[t][rg], 0.f);
            }
            if (t < 2) {
                *(f16x4*)&s0buf2[px * 40 + t * 16 + q * 4] = h0;
                *(f16x4*)&s1buf2[px * 40 + t * 16 + q * 4] = h1;
            } else if (q == 0) {  // ch 32..35 only
                *(f16x4*)&s0buf2[px * 40 + 32] = h0;
                *(f16x4*)&s1buf2[px * 40 + 32] = h1;
            }
        }
        const f16x8 B3a0 = *(const f16x8*)&s0buf2[px * 40 + q * 8];
        const f16x8 B3b0 = *(const f16x8*)&s1buf2[px * 40 + q * 8];
        f16x8 B3a1 = {0, 0, 0, 0, 0, 0, 0, 0};
        f16x8 B3b1 = {0, 0, 0, 0, 0, 0, 0, 0};
        if (q == 0) {  // slice2: j0..3 = ch32..35, j4 = bias (=1)
            const f16x4 t0 = *(const f16x4*)&s0buf2[px * 40 + 32];
            const f16x4 t1 = *(const f16x4*)&s1buf2[px * 40 + 32];
#pragma unroll
            for (int j = 0; j < 4; ++j) { B3a1[j] = t0[j]; B3b1[j] = t1[j]; }
            B3a1[4] = (_Float16)1.f;
            B3b1[4] = (_Float16)1.f;
        }

        // ---- layer 3 (two K-slices, bias via k=36) ----
        f32x4 D3a[3], D3b[3];
#pragma unroll
        for (int t = 0; t < 3; ++t) {
            D3a[t] = __builtin_amdgcn_mfma_f32_16x16x32_f16(A3s0[t], B3a0, zf4, 0, 0, 0);
            D3a[t] = __builtin_amdgcn_mfma_f32_16x16x32_f16(A3s1[t], B3a1, D3a[t], 0, 0, 0);
            D3b[t] = __builtin_amdgcn_mfma_f32_16x16x32_f16(A3s0[t], B3b0, zf4, 0, 0, 0);
            D3b[t] = __builtin_amdgcn_mfma_f32_16x16x32_f16(A3s1[t], B3b1, D3b[t], 0, 0, 0);
        }

        // ---- layer 4 epilogue: dot + shuffles; row maxes stashed in LDS ----
        float sa = 0.f, sb = 0.f;
#pragma unroll
        for (int t = 0; t < 3; ++t)
#pragma unroll
            for (int rg = 0; rg < 4; ++rg) {
                sa = fmaf(w4r[t][rg], fmaxf(D3a[t][rg], 0.f), sa);
                sb = fmaf(w4r[t][rg], fmaxf(D3b[t][rg], 0.f), sb);
            }
        sa += __shfl_xor(sa, 16, 64); sb += __shfl_xor(sb, 16, 64);
        sa += __shfl_xor(sa, 32, 64); sb += __shfl_xor(sb, 32, 64);
        sa += b4s; sb += b4s;

        sa = colok ? sa : NEG_INF;
        sb = colok ? sb : NEG_INF;
        colmax = fmaxf(colmax, fmaxf(sa, sb));

        float m0 = sa, m1 = sb;
        m0 = fmaxf(m0, __shfl_xor(m0, 1, 64)); m1 = fmaxf(m1, __shfl_xor(m1, 1, 64));
        m0 = fmaxf(m0, __shfl_xor(m0, 2, 64)); m1 = fmaxf(m1, __shfl_xor(m1, 2, 64));
        m0 = fmaxf(m0, __shfl_xor(m0, 4, 64)); m1 = fmaxf(m1, __shfl_xor(m1, 4, 64));
        m0 = fmaxf(m0, __shfl_xor(m0, 8, 64)); m1 = fmaxf(m1, __shfl_xor(m1, 8, 64));
        if (tx == 0) {
            // LDS store (lgkm) instead of global atomic (vmcnt): keeps the
            // loop-top vmcnt drain free of ~1000-cyc atomic round trips.
            rowmax_s[wv][it * 2] = m0;
            rowmax_s[wv][it * 2 + 1] = m1;
        }
    }

    // column maxes (one atomic per column lane, outside the loop as before)
    if (q == 0 && colok) atomicMax(&colbuck[col], fenc(colmax));

    // row-max flush: reduce the 4 waves' stashes, 16 atomics per block total
    __syncthreads();
    if (wv == 0 && tx < 16) {
        float m = fmaxf(fmaxf(rowmax_s[0][tx], rowmax_s[1][tx]),
                        fmaxf(rowmax_s[2][tx], rowmax_s[3][tx]));
        atomicMax(&rowbuck[rb + tx], fenc(m));
    }
}

extern "C" void kernel_launch(void* const* d_in, const int* in_sizes, int n_in,
                              void* d_out, int out_size, void* d_ws, size_t ws_size,
                              hipStream_t stream) {
    const float* in = (const float*)d_in[0];
    // d_in[1] = T_out (unused), d_in[2] = T_indices (identity, unused)
    const float* w1 = (const float*)d_in[3];
    const float* b1 = (const float*)d_in[4];
    const float* w2 = (const float*)d_in[5];
    const float* b2 = (const float*)d_in[6];
    const float* w3 = (const float*)d_in[7];
    const float* b3 = (const float*)d_in[8];
    const float* w4 = (const float*)d_in[9];
    const float* b4 = (const float*)d_in[10];

    unsigned* buck = (unsigned*)d_out;  // [0,2000) row maxes, [2000,3000) col maxes

    init_buckets<<<(3000 + 255) / 256, 256, 0, stream>>>(buck, 3000);

    dim3 block(64, 4);
    dim3 grid(16, 125);  // 64 cols x 16 rows per block (R7 equilibrium)
    mlp_max_mfma<<<grid, block, 0, stream>>>(in, w1, b1, w2, b2, w3, b3, w4, b4,
                                             buck, buck + 2000);

    decode_buckets<<<(3000 + 255) / 256, 256, 0, stream>>>(buck, 3000);
}

// Round 12
// 224.262 us; speedup vs baseline: 1.7779x; 1.1252x over previous
//
#include <hip/hip_runtime.h>

typedef _Float16 f16x8 __attribute__((ext_vector_type(8)));
typedef _Float16 f16x4 __attribute__((ext_vector_type(4)));
typedef float f32x4 __attribute__((ext_vector_type(4)));

#define HH 2000
#define WW 1000
#define HWSZ (HH * WW)
#define NEG_INF (-3.0e38f)

// ---- monotone float<->uint encoding for atomicMax on floats ----
__device__ __forceinline__ unsigned fenc(float f) {
    unsigned u = __float_as_uint(f);
    return (u & 0x80000000u) ? ~u : (u | 0x80000000u);
}
__device__ __forceinline__ float fdec(unsigned k) {
    unsigned u = (k & 0x80000000u) ? (k & 0x7fffffffu) : ~k;
    return __uint_as_float(u);
}

__global__ void init_buckets(unsigned* __restrict__ buck, int n) {
    int i = blockIdx.x * blockDim.x + threadIdx.x;
    if (i < n) buck[i] = 0u;
}

__global__ void decode_buckets(unsigned* __restrict__ buck, int n) {
    int i = blockIdx.x * blockDim.x + threadIdx.x;
    if (i < n) {
        unsigned k = buck[i];
        ((float*)buck)[i] = fdec(k);
    }
}

// MFMA 16x16x32 f16 layouts (gfx950, verified R6-R11 absmax=2e-3):
//   A: lane holds A[m=lane&15][k=(lane>>4)*8+j]
//   B: lane holds B[k=(lane>>4)*8+j][n=lane&15]
//   D: lane holds D[row=(lane>>4)*4+reg][col=lane&15]
// A = weights (m = out-ch), B = activations (n = pixel).
// Biases folded in via constant-1 channel (K 9->10, 18->19, 36->37).
//
// R12 = R11 (best: 144us) with ONE structural change: ONE WAVE PER BLOCK.
// R11's 4-wave blocks shared nothing but a final reduce + barrier; LDS was
// per-wave-private. 8000 x 64-thread blocks (same 16col x 16row tile per
// wave, same per-wave prologue amortization) give the scheduler 31
// independent 5.1KB blocks/CU to pack instead of 7 lock-step 21KB blocks,
// delete the barrier, and let waves retire independently. Row maxes
// accumulate in a per-lane register (lane i owns row rb+i) via cndmask.

__global__ __launch_bounds__(64) void mlp_max_mfma(
    const float* __restrict__ in,
    const float* __restrict__ w1, const float* __restrict__ b1,
    const float* __restrict__ w2, const float* __restrict__ b2,
    const float* __restrict__ w3, const float* __restrict__ b3,
    const float* __restrict__ w4, const float* __restrict__ b4,
    unsigned* __restrict__ rowbuck, unsigned* __restrict__ colbuck) {
    // 2 row-slots x (buf1[16][40] + buf2[16][40]) halves = 5120 B total.
    // stride 40 halves = 80B keeps every b128 16B-aligned. Every byte read
    // is written earlier in the same iteration -> no zero-init needed.
    __shared__ _Float16 lds[2 * 1280];

    const int tx = threadIdx.x;   // 0..63
    const int px = tx & 15;
    const int q = tx >> 4;

    _Float16* s0buf1 = &lds[0];
    _Float16* s0buf2 = &lds[640];
    _Float16* s1buf1 = &lds[1280];
    _Float16* s1buf2 = &lds[1920];

    // ---- weight A-fragments (persistent, reused every iteration) ----
    f16x8 A1[2], A2[3], A3s0[3], A3s1[3];
#pragma unroll
    for (int t = 0; t < 2; ++t) {
        const int m = t * 16 + px;
#pragma unroll
        for (int j = 0; j < 8; ++j) {
            const int k = q * 8 + j;
            float v = 0.f;
            if (m < 18) {
                if (k < 9) v = w1[m * 9 + k];
                else if (k == 9) v = b1[m];
            }
            A1[t][j] = (_Float16)v;
        }
    }
#pragma unroll
    for (int t = 0; t < 3; ++t) {
        const int m = t * 16 + px;
#pragma unroll
        for (int j = 0; j < 8; ++j) {
            const int k = q * 8 + j;
            float v = 0.f;
            if (m < 36) {
                if (k < 18) v = w2[m * 18 + k];
                else if (k == 18) v = b2[m];
            }
            A2[t][j] = (_Float16)v;
        }
    }
#pragma unroll
    for (int t = 0; t < 3; ++t) {
        const int m = t * 16 + px;
#pragma unroll
        for (int j = 0; j < 8; ++j) {
            const int k = q * 8 + j;
            float v = 0.f;
            if (m < 36 && k < 32) v = w3[m * 36 + k];
            A3s0[t][j] = (_Float16)v;
            float v2 = 0.f;
            const int k2 = 32 + k;  // slice 2: ch 32..35 real, 36 = bias
            if (m < 36) {
                if (k2 < 36) v2 = w3[m * 36 + k2];
                else if (k2 == 36) v2 = b3[m];
            }
            A3s1[t][j] = (_Float16)v2;
        }
    }

    float w4r[3][4];
#pragma unroll
    for (int t = 0; t < 3; ++t)
#pragma unroll
        for (int rg = 0; rg < 4; ++rg) {
            const int ch = t * 16 + q * 4 + rg;
            w4r[t][rg] = (ch < 36) ? w4[ch] : 0.f;
        }
    const float b4s = b4[0];

    const int col = blockIdx.x * 16 + px;
    const int colc = (col < WW) ? col : (WW - 1);
    const bool colok = (col < WW);
    const int rb = blockIdx.y * 16;

    float colmax = NEG_INF;
    float rowm = NEG_INF;   // lane i (i<16) accumulates row rb+i's max
    const f32x4 zf4 = {0.f, 0.f, 0.f, 0.f};

#pragma unroll 1
    for (int it = 0; it < 8; ++it) {
        const int r0 = rb + it * 2;
        const int r1 = r0 + 1;

        // ---- inputs, both rows (K=10: ch 0..8 + constant-1 bias channel) ----
        f16x8 bin0, bin1;
#pragma unroll
        for (int j = 0; j < 8; ++j) {
            const int c = q * 8 + j;
            float v0 = 0.f, v1 = 0.f;
            if (c < 9) {
                v0 = in[c * HWSZ + r0 * WW + colc];
                v1 = in[c * HWSZ + r1 * WW + colc];
            } else if (c == 9) {
                v0 = 1.f; v1 = 1.f;
            }
            bin0[j] = (_Float16)v0;
            bin1[j] = (_Float16)v1;
        }

        // ---- layer 1 (bias via k=9) ----
        f32x4 D1a[2], D1b[2];
#pragma unroll
        for (int t = 0; t < 2; ++t) {
            D1a[t] = __builtin_amdgcn_mfma_f32_16x16x32_f16(A1[t], bin0, zf4, 0, 0, 0);
            D1b[t] = __builtin_amdgcn_mfma_f32_16x16x32_f16(A1[t], bin1, zf4, 0, 0, 0);
        }
#pragma unroll
        for (int t = 0; t < 2; ++t) {
            f16x4 h0, h1;
#pragma unroll
            for (int rg = 0; rg < 4; ++rg) {
                h0[rg] = (_Float16)fmaxf(D1a[t][rg], 0.f);
                h1[rg] = (_Float16)fmaxf(D1b[t][rg], 0.f);
            }
            if (t == 1 && q == 0) { h0[2] = (_Float16)1.f; h1[2] = (_Float16)1.f; }  // ch18 = 1
            *(f16x4*)&s0buf1[px * 40 + t * 16 + q * 4] = h0;
            *(f16x4*)&s1buf1[px * 40 + t * 16 + q * 4] = h1;
        }
        const f16x8 B2a = *(const f16x8*)&s0buf1[px * 40 + q * 8];
        const f16x8 B2b = *(const f16x8*)&s1buf1[px * 40 + q * 8];

        // ---- layer 2 (bias via k=18) ----
        f32x4 D2a[3], D2b[3];
#pragma unroll
        for (int t = 0; t < 3; ++t) {
            D2a[t] = __builtin_amdgcn_mfma_f32_16x16x32_f16(A2[t], B2a, zf4, 0, 0, 0);
            D2b[t] = __builtin_amdgcn_mfma_f32_16x16x32_f16(A2[t], B2b, zf4, 0, 0, 0);
        }
#pragma unroll
        for (int t = 0; t < 3; ++t) {
            f16x4 h0, h1;
#pragma unroll
            for (int rg = 0; rg < 4; ++rg) {
                h0[rg] = (_Float16)fmaxf(D2a[t][rg], 0.f);
                h1[rg] = (_Float16)fmaxf(D2b[t][rg], 0.f);
            }
            if (t < 2) {
                *(f16x4*)&s0buf2[px * 40 + t * 16 + q * 4] = h0;
                *(f16x4*)&s1buf2[px * 40 + t * 16 + q * 4] = h1;
            } else if (q == 0) {  // ch 32..35 only
                *(f16x4*)&s0buf2[px * 40 + 32] = h0;
                *(f16x4*)&s1buf2[px * 40 + 32] = h1;
            }
        }
        const f16x8 B3a0 = *(const f16x8*)&s0buf2[px * 40 + q * 8];
        const f16x8 B3b0 = *(const f16x8*)&s1buf2[px * 40 + q * 8];
        f16x8 B3a1 = {0, 0, 0, 0, 0, 0, 0, 0};
        f16x8 B3b1 = {0, 0, 0, 0, 0, 0, 0, 0};
        if (q == 0) {  // slice2: j0..3 = ch32..35, j4 = bias (=1)
            const f16x4 t0 = *(const f16x4*)&s0buf2[px * 40 + 32];
            const f16x4 t1 = *(const f16x4*)&s1buf2[px * 40 + 32];
#pragma unroll
            for (int j = 0; j < 4; ++j) { B3a1[j] = t0[j]; B3b1[j] = t1[j]; }
            B3a1[4] = (_Float16)1.f;
            B3b1[4] = (_Float16)1.f;
        }

        // ---- layer 3 (two K-slices, bias via k=36) ----
        f32x4 D3a[3], D3b[3];
#pragma unroll
        for (int t = 0; t < 3; ++t) {
            D3a[t] = __builtin_amdgcn_mfma_f32_16x16x32_f16(A3s0[t], B3a0, zf4, 0, 0, 0);
            D3a[t] = __builtin_amdgcn_mfma_f32_16x16x32_f16(A3s1[t], B3a1, D3a[t], 0, 0, 0);
            D3b[t] = __builtin_amdgcn_mfma_f32_16x16x32_f16(A3s0[t], B3b0, zf4, 0, 0, 0);
            D3b[t] = __builtin_amdgcn_mfma_f32_16x16x32_f16(A3s1[t], B3b1, D3b[t], 0, 0, 0);
        }

        // ---- layer 4 epilogue: dot + shuffles; row max kept in registers ----
        float sa = 0.f, sb = 0.f;
#pragma unroll
        for (int t = 0; t < 3; ++t)
#pragma unroll
            for (int rg = 0; rg < 4; ++rg) {
                sa = fmaf(w4r[t][rg], fmaxf(D3a[t][rg], 0.f), sa);
                sb = fmaf(w4r[t][rg], fmaxf(D3b[t][rg], 0.f), sb);
            }
        sa += __shfl_xor(sa, 16, 64); sb += __shfl_xor(sb, 16, 64);
        sa += __shfl_xor(sa, 32, 64); sb += __shfl_xor(sb, 32, 64);
        sa += b4s; sb += b4s;

        sa = colok ? sa : NEG_INF;
        sb = colok ? sb : NEG_INF;
        colmax = fmaxf(colmax, fmaxf(sa, sb));

        float m0 = sa, m1 = sb;
        m0 = fmaxf(m0, __shfl_xor(m0, 1, 64)); m1 = fmaxf(m1, __shfl_xor(m1, 1, 64));
        m0 = fmaxf(m0, __shfl_xor(m0, 2, 64)); m1 = fmaxf(m1, __shfl_xor(m1, 2, 64));
        m0 = fmaxf(m0, __shfl_xor(m0, 4, 64)); m1 = fmaxf(m1, __shfl_xor(m1, 4, 64));
        m0 = fmaxf(m0, __shfl_xor(m0, 8, 64)); m1 = fmaxf(m1, __shfl_xor(m1, 8, 64));
        // every lane now holds the full row maxes; lane i owns row rb+i
        rowm = (tx == it * 2) ? m0 : rowm;
        rowm = (tx == it * 2 + 1) ? m1 : rowm;
    }

    // end-of-block flush: no barrier needed (single wave)
    if (q == 0 && colok) atomicMax(&colbuck[col], fenc(colmax));
    if (tx < 16) atomicMax(&rowbuck[rb + tx], fenc(rowm));
}

extern "C" void kernel_launch(void* const* d_in, const int* in_sizes, int n_in,
                              void* d_out, int out_size, void* d_ws, size_t ws_size,
                              hipStream_t stream) {
    const float* in = (const float*)d_in[0];
    // d_in[1] = T_out (unused), d_in[2] = T_indices (identity, unused)
    const float* w1 = (const float*)d_in[3];
    const float* b1 = (const float*)d_in[4];
    const float* w2 = (const float*)d_in[5];
    const float* b2 = (const float*)d_in[6];
    const float* w3 = (const float*)d_in[7];
    const float* b3 = (const float*)d_in[8];
    const float* w4 = (const float*)d_in[9];
    const float* b4 = (const float*)d_in[10];

    unsigned* buck = (unsigned*)d_out;  // [0,2000) row maxes, [2000,3000) col maxes

    init_buckets<<<(3000 + 255) / 256, 256, 0, stream>>>(buck, 3000);

    dim3 block(64);
    dim3 grid(63, 125);  // 63*16=1008 >= 1000 cols ; 125*16=2000 rows exactly
    mlp_max_mfma<<<grid, block, 0, stream>>>(in, w1, b1, w2, b2, w3, b3, w4, b4,
                                             buck, buck + 2000);

    decode_buckets<<<(3000 + 255) / 256, 256, 0, stream>>>(buck, 3000);
}

// Round 13
// 218.133 us; speedup vs baseline: 1.8278x; 1.0281x over previous
//
#include <hip/hip_runtime.h>

typedef _Float16 f16x8 __attribute__((ext_vector_type(8)));
typedef _Float16 f16x4 __attribute__((ext_vector_type(4)));
typedef float f32x4 __attribute__((ext_vector_type(4)));

#define HH 2000
#define WW 1000
#define HWSZ (HH * WW)
#define NEG_INF (-3.0e38f)

// ---- monotone float<->uint encoding for atomicMax on floats ----
__device__ __forceinline__ unsigned fenc(float f) {
    unsigned u = __float_as_uint(f);
    return (u & 0x80000000u) ? ~u : (u | 0x80000000u);
}
__device__ __forceinline__ float fdec(unsigned k) {
    unsigned u = (k & 0x80000000u) ? (k & 0x7fffffffu) : ~k;
    return __uint_as_float(u);
}

__global__ void init_buckets(unsigned* __restrict__ buck, int n) {
    int i = blockIdx.x * blockDim.x + threadIdx.x;
    if (i < n) buck[i] = 0u;
}

__global__ void decode_buckets(unsigned* __restrict__ buck, int n) {
    int i = blockIdx.x * blockDim.x + threadIdx.x;
    if (i < n) {
        unsigned k = buck[i];
        ((float*)buck)[i] = fdec(k);
    }
}

// MFMA 16x16x32 f16 layouts (gfx950, verified R6-R12 absmax=2e-3):
//   A: lane holds A[m=lane&15][k=(lane>>4)*8+j]
//   B: lane holds B[k=(lane>>4)*8+j][n=lane&15]
//   D: lane holds D[row=(lane>>4)*4+reg][col=lane&15]
// A = weights (m = out-ch), B = activations (n = pixel).
// Biases folded in via constant-1 channel (K 9->10, 18->19, 36->37).
//
// R13 = R12 (best: 117us) + two changes:
// (a) 2 independent waves per block (no barrier, no shared state). R12's
//     1-wave blocks hit the per-CU workgroup-slot cap (~16) at 12.8 waves/CU;
//     2 waves/slot doubles achievable residency (4000 blocks = 15.6/CU).
// (b) row-max via conflict-free ds_write scatter into a per-wave [row][px]
//     tile + one end-of-wave reduce, replacing 8 dependent max-shuffles
//     (~480 cyc of serial DS latency) per iteration. After the 2 sum-shuffles
//     every lane holds s(px), so q==0 lanes scatter row r0, q==1 row r1.

__global__ __launch_bounds__(128) void mlp_max_mfma(
    const float* __restrict__ in,
    const float* __restrict__ w1, const float* __restrict__ b1,
    const float* __restrict__ w2, const float* __restrict__ b2,
    const float* __restrict__ w3, const float* __restrict__ b3,
    const float* __restrict__ w4, const float* __restrict__ b4,
    unsigned* __restrict__ rowbuck, unsigned* __restrict__ colbuck) {
    // per wave: 2 row-slots x (buf1[16][40] + buf2[16][40]) halves = 5120 B.
    // stride 40 halves = 80B keeps every b128 16B-aligned. Every byte read
    // is written earlier in the same iteration -> no zero-init needed.
    __shared__ _Float16 lds[2][2 * 1280];
    __shared__ float rowsm[2][16][16];   // [wave][row-in-block][px]

    const int tx = threadIdx.x;   // 0..63
    const int wv = threadIdx.y;   // 0..1 (independent waves)
    const int px = tx & 15;
    const int q = tx >> 4;

    _Float16* s0buf1 = &lds[wv][0];
    _Float16* s0buf2 = &lds[wv][640];
    _Float16* s1buf1 = &lds[wv][1280];
    _Float16* s1buf2 = &lds[wv][1920];

    // ---- weight A-fragments (persistent, reused every iteration) ----
    f16x8 A1[2], A2[3], A3s0[3], A3s1[3];
#pragma unroll
    for (int t = 0; t < 2; ++t) {
        const int m = t * 16 + px;
#pragma unroll
        for (int j = 0; j < 8; ++j) {
            const int k = q * 8 + j;
            float v = 0.f;
            if (m < 18) {
                if (k < 9) v = w1[m * 9 + k];
                else if (k == 9) v = b1[m];
            }
            A1[t][j] = (_Float16)v;
        }
    }
#pragma unroll
    for (int t = 0; t < 3; ++t) {
        const int m = t * 16 + px;
#pragma unroll
        for (int j = 0; j < 8; ++j) {
            const int k = q * 8 + j;
            float v = 0.f;
            if (m < 36) {
                if (k < 18) v = w2[m * 18 + k];
                else if (k == 18) v = b2[m];
            }
            A2[t][j] = (_Float16)v;
        }
    }
#pragma unroll
    for (int t = 0; t < 3; ++t) {
        const int m = t * 16 + px;
#pragma unroll
        for (int j = 0; j < 8; ++j) {
            const int k = q * 8 + j;
            float v = 0.f;
            if (m < 36 && k < 32) v = w3[m * 36 + k];
            A3s0[t][j] = (_Float16)v;
            float v2 = 0.f;
            const int k2 = 32 + k;  // slice 2: ch 32..35 real, 36 = bias
            if (m < 36) {
                if (k2 < 36) v2 = w3[m * 36 + k2];
                else if (k2 == 36) v2 = b3[m];
            }
            A3s1[t][j] = (_Float16)v2;
        }
    }

    float w4r[3][4];
#pragma unroll
    for (int t = 0; t < 3; ++t)
#pragma unroll
        for (int rg = 0; rg < 4; ++rg) {
            const int ch = t * 16 + q * 4 + rg;
            w4r[t][rg] = (ch < 36) ? w4[ch] : 0.f;
        }
    const float b4s = b4[0];

    const int col = blockIdx.x * 32 + wv * 16 + px;
    const int colc = (col < WW) ? col : (WW - 1);
    const bool colok = (col < WW);
    const int rb = blockIdx.y * 16;

    float colmax = NEG_INF;
    const f32x4 zf4 = {0.f, 0.f, 0.f, 0.f};

#pragma unroll 1
    for (int it = 0; it < 8; ++it) {
        const int r0 = rb + it * 2;
        const int r1 = r0 + 1;

        // ---- inputs, both rows (K=10: ch 0..8 + constant-1 bias channel) ----
        f16x8 bin0, bin1;
#pragma unroll
        for (int j = 0; j < 8; ++j) {
            const int c = q * 8 + j;
            float v0 = 0.f, v1 = 0.f;
            if (c < 9) {
                v0 = in[c * HWSZ + r0 * WW + colc];
                v1 = in[c * HWSZ + r1 * WW + colc];
            } else if (c == 9) {
                v0 = 1.f; v1 = 1.f;
            }
            bin0[j] = (_Float16)v0;
            bin1[j] = (_Float16)v1;
        }

        // ---- layer 1 (bias via k=9) ----
        f32x4 D1a[2], D1b[2];
#pragma unroll
        for (int t = 0; t < 2; ++t) {
            D1a[t] = __builtin_amdgcn_mfma_f32_16x16x32_f16(A1[t], bin0, zf4, 0, 0, 0);
            D1b[t] = __builtin_amdgcn_mfma_f32_16x16x32_f16(A1[t], bin1, zf4, 0, 0, 0);
        }
#pragma unroll
        for (int t = 0; t < 2; ++t) {
            f16x4 h0, h1;
#pragma unroll
            for (int rg = 0; rg < 4; ++rg) {
                h0[rg] = (_Float16)fmaxf(D1a[t][rg], 0.f);
                h1[rg] = (_Float16)fmaxf(D1b[t][rg], 0.f);
            }
            if (t == 1 && q == 0) { h0[2] = (_Float16)1.f; h1[2] = (_Float16)1.f; }  // ch18 = 1
            *(f16x4*)&s0buf1[px * 40 + t * 16 + q * 4] = h0;
            *(f16x4*)&s1buf1[px * 40 + t * 16 + q * 4] = h1;
        }
        const f16x8 B2a = *(const f16x8*)&s0buf1[px * 40 + q * 8];
        const f16x8 B2b = *(const f16x8*)&s1buf1[px * 40 + q * 8];

        // ---- layer 2 (bias via k=18) ----
        f32x4 D2a[3], D2b[3];
#pragma unroll
        for (int t = 0; t < 3; ++t) {
            D2a[t] = __builtin_amdgcn_mfma_f32_16x16x32_f16(A2[t], B2a, zf4, 0, 0, 0);
            D2b[t] = __builtin_amdgcn_mfma_f32_16x16x32_f16(A2[t], B2b, zf4, 0, 0, 0);
        }
#pragma unroll
        for (int t = 0; t < 3; ++t) {
            f16x4 h0, h1;
#pragma unroll
            for (int rg = 0; rg < 4; ++rg) {
                h0[rg] = (_Float16)fmaxf(D2a[t][rg], 0.f);
                h1[rg] = (_Float16)fmaxf(D2b[t][rg], 0.f);
            }
            if (t < 2) {
                *(f16x4*)&s0buf2[px * 40 + t * 16 + q * 4] = h0;
                *(f16x4*)&s1buf2[px * 40 + t * 16 + q * 4] = h1;
            } else if (q == 0) {  // ch 32..35 only
                *(f16x4*)&s0buf2[px * 40 + 32] = h0;
                *(f16x4*)&s1buf2[px * 40 + 32] = h1;
            }
        }
        const f16x8 B3a0 = *(const f16x8*)&s0buf2[px * 40 + q * 8];
        const f16x8 B3b0 = *(const f16x8*)&s1buf2[px * 40 + q * 8];
        f16x8 B3a1 = {0, 0, 0, 0, 0, 0, 0, 0};
        f16x8 B3b1 = {0, 0, 0, 0, 0, 0, 0, 0};
        if (q == 0) {  // slice2: j0..3 = ch32..35, j4 = bias (=1)
            const f16x4 t0 = *(const f16x4*)&s0buf2[px * 40 + 32];
            const f16x4 t1 = *(const f16x4*)&s1buf2[px * 40 + 32];
#pragma unroll
            for (int j = 0; j < 4; ++j) { B3a1[j] = t0[j]; B3b1[j] = t1[j]; }
            B3a1[4] = (_Float16)1.f;
            B3b1[4] = (_Float16)1.f;
        }

        // ---- layer 3 (two K-slices, bias via k=36) ----
        f32x4 D3a[3], D3b[3];
#pragma unroll
        for (int t = 0; t < 3; ++t) {
            D3a[t] = __builtin_amdgcn_mfma_f32_16x16x32_f16(A3s0[t], B3a0, zf4, 0, 0, 0);
            D3a[t] = __builtin_amdgcn_mfma_f32_16x16x32_f16(A3s1[t], B3a1, D3a[t], 0, 0, 0);
            D3b[t] = __builtin_amdgcn_mfma_f32_16x16x32_f16(A3s0[t], B3b0, zf4, 0, 0, 0);
            D3b[t] = __builtin_amdgcn_mfma_f32_16x16x32_f16(A3s1[t], B3b1, D3b[t], 0, 0, 0);
        }

        // ---- layer 4 epilogue: dot + 2 sum-shuffles; row-max via LDS scatter ----
        float sa = 0.f, sb = 0.f;
#pragma unroll
        for (int t = 0; t < 3; ++t)
#pragma unroll
            for (int rg = 0; rg < 4; ++rg) {
                sa = fmaf(w4r[t][rg], fmaxf(D3a[t][rg], 0.f), sa);
                sb = fmaf(w4r[t][rg], fmaxf(D3b[t][rg], 0.f), sb);
            }
        sa += __shfl_xor(sa, 16, 64); sb += __shfl_xor(sb, 16, 64);
        sa += __shfl_xor(sa, 32, 64); sb += __shfl_xor(sb, 32, 64);
        sa += b4s; sb += b4s;

        sa = colok ? sa : NEG_INF;
        sb = colok ? sb : NEG_INF;
        colmax = fmaxf(colmax, fmaxf(sa, sb));

        // every lane holds the full s(px); scatter to [row][px], fire-and-forget.
        // banks: row even->0..15, row odd->16..31 -> 32 active lanes, 0 conflicts.
        if (q == 0) rowsm[wv][it * 2][px] = sa;
        else if (q == 1) rowsm[wv][it * 2 + 1][px] = sb;
    }

    // ---- end-of-wave flush (no barrier: rowsm slice is wave-private) ----
    if (q == 0 && colok) atomicMax(&colbuck[col], fenc(colmax));
    if (tx < 16) {
        const f32x4 v0 = *(const f32x4*)&rowsm[wv][tx][0];
        const f32x4 v1 = *(const f32x4*)&rowsm[wv][tx][4];
        const f32x4 v2 = *(const f32x4*)&rowsm[wv][tx][8];
        const f32x4 v3 = *(const f32x4*)&rowsm[wv][tx][12];
        float m = NEG_INF;
#pragma unroll
        for (int j = 0; j < 4; ++j) {
            m = fmaxf(m, fmaxf(fmaxf(v0[j], v1[j]), fmaxf(v2[j], v3[j])));
        }
        atomicMax(&rowbuck[rb + tx], fenc(m));
    }
}

extern "C" void kernel_launch(void* const* d_in, const int* in_sizes, int n_in,
                              void* d_out, int out_size, void* d_ws, size_t ws_size,
                              hipStream_t stream) {
    const float* in = (const float*)d_in[0];
    // d_in[1] = T_out (unused), d_in[2] = T_indices (identity, unused)
    const float* w1 = (const float*)d_in[3];
    const float* b1 = (const float*)d_in[4];
    const float* w2 = (const float*)d_in[5];
    const float* b2 = (const float*)d_in[6];
    const float* w3 = (const float*)d_in[7];
    const float* b3 = (const float*)d_in[8];
    const float* w4 = (const float*)d_in[9];
    const float* b4 = (const float*)d_in[10];

    unsigned* buck = (unsigned*)d_out;  // [0,2000) row maxes, [2000,3000) col maxes

    init_buckets<<<(3000 + 255) / 256, 256, 0, stream>>>(buck, 3000);

    dim3 block(64, 2);
    dim3 grid(32, 125);  // 32*32=1024 >= 1000 cols ; 125*16=2000 rows exactly
    mlp_max_mfma<<<grid, block, 0, stream>>>(in, w1, b1, w2, b2, w3, b3, w4, b4,
                                             buck, buck + 2000);

    decode_buckets<<<(3000 + 255) / 256, 256, 0, stream>>>(buck, 3000);
}